// Round 3
// baseline (186.891 us; speedup 1.0000x reference)
//
#include <hip/hip_runtime.h>
#include <hip/hip_bf16.h>

// Contrastive loss, B=8192, D=128, 100 classes, margin=2.
// R3: LDS-staged gram tiles. K=128 fits in one staging pass (no K-loop).
// Per 128x128 block: coalesced global->LDS (row stride padded to 272B so
// ds_read_b128 fragments are conflict-free-ish), 4 waves x 64x64 subtiles,
// 64 MFMAs (16x16x32 bf16) per wave. Triangle-only grid, fused finalize.

#define BN 8192
#define DD 128
#define NTILES 64                         // BN / 128
#define NBLOCKS (NTILES * (NTILES + 1) / 2)   // 2080
#define LDSTRIDE 136                      // shorts: 272B row stride, %128B = 16B -> bank shift 4

typedef __attribute__((ext_vector_type(8))) short bf16x8;   // 8 bf16 = 4 VGPRs
typedef __attribute__((ext_vector_type(4))) float f32x4;

// fp32 -> bf16 (RN) + row squared-norms of the rounded values; also zeroes acc.
__global__ __launch_bounds__(256) void prep_kernel(const float* __restrict__ f,
        __hip_bfloat16* __restrict__ fb, float* __restrict__ sq,
        float* __restrict__ acc) {
    int idx = blockIdx.x * blockDim.x + threadIdx.x;  // BN*64 threads
    if (idx < 4) acc[idx] = 0.f;          // pos, neg, cnt, done-counter
    int row = idx >> 6, lane = idx & 63;
    float2 v = ((const float2*)(f + (size_t)row * DD))[lane];
    __hip_bfloat162 b2;
    b2.x = __float2bfloat16(v.x);
    b2.y = __float2bfloat16(v.y);
    ((__hip_bfloat162*)(fb + (size_t)row * DD))[lane] = b2;
    float xr = __bfloat162float(b2.x), yr = __bfloat162float(b2.y);
    float s = xr * xr + yr * yr;
#pragma unroll
    for (int off = 32; off > 0; off >>= 1) s += __shfl_down(s, off, 64);
    if (lane == 0) sq[row] = s;
}

__global__ __launch_bounds__(256) void pair_kernel(
        const __hip_bfloat16* __restrict__ fb, const int* __restrict__ labels,
        const float* __restrict__ sq, float* __restrict__ acc,
        float* __restrict__ out) {
    // triangular decode: block t -> (bx <= by); i-tile = bx, j-tile = by
    const int t = blockIdx.x;
    int by = (int)((sqrtf(8.f * (float)t + 1.f) - 1.f) * 0.5f);
    while ((by + 1) * (by + 2) / 2 <= t) by++;
    while (by * (by + 1) / 2 > t) by--;
    const int bx = t - by * (by + 1) / 2;
    const int i0 = bx * 128, j0 = by * 128;
    const bool diag = (bx == by);
    const int bsel = diag ? 0 : 1;

    __shared__ __hip_bfloat16 tiles[2][128][LDSTRIDE];  // 69.6 KB -> 2 blocks/CU

    const int tid = threadIdx.x;
    const int wave = tid >> 6, lane = tid & 63;
    const int wx = wave & 1, wy = wave >> 1;   // j / i subtile of the 128x128 block
    const int l15 = lane & 15, quad = lane >> 4;

    // ---- stage A (and B unless diagonal): 2048 16B-chunks each, coalesced ----
#pragma unroll
    for (int it = 0; it < 8; it++) {
        int c = it * 256 + tid;                // 0..2047
        int r = c >> 4, col = c & 15;          // 16 chunks of 16B per 256B row
        float4 va = *(const float4*)(fb + (size_t)(i0 + r) * DD + col * 8);
        *(float4*)&tiles[0][r][col * 8] = va;
    }
    if (!diag) {
#pragma unroll
        for (int it = 0; it < 8; it++) {
            int c = it * 256 + tid;
            int r = c >> 4, col = c & 15;
            float4 vb = *(const float4*)(fb + (size_t)(j0 + r) * DD + col * 8);
            *(float4*)&tiles[1][r][col * 8] = vb;
        }
    }
    __syncthreads();

    float pos = 0.f, neg = 0.f, cnt = 0.f;

    // diag blocks: waves with wx<wy cover only gi>gj -> nothing to compute
    if (!(diag && wx < wy)) {
        f32x4 acc4[4][4];
#pragma unroll
        for (int a = 0; a < 4; a++)
#pragma unroll
            for (int b = 0; b < 4; b++) acc4[a][b] = (f32x4){0.f, 0.f, 0.f, 0.f};

#pragma unroll
        for (int ks = 0; ks < 4; ks++) {
            const int kofs = ks * 32 + quad * 8;
            bf16x8 af[4], bg[4];
#pragma unroll
            for (int tt = 0; tt < 4; tt++)
                af[tt] = *(const bf16x8*)&tiles[0][wy * 64 + tt * 16 + l15][kofs];
#pragma unroll
            for (int tt = 0; tt < 4; tt++)
                bg[tt] = *(const bf16x8*)&tiles[bsel][wx * 64 + tt * 16 + l15][kofs];
#pragma unroll
            for (int mi = 0; mi < 4; mi++)
#pragma unroll
                for (int ni = 0; ni < 4; ni++)
                    acc4[mi][ni] = __builtin_amdgcn_mfma_f32_16x16x32_bf16(
                        af[mi], bg[ni], acc4[mi][ni], 0, 0, 0);
        }

        // epilogue. C/D: col = lane&15 (j), row = quad*4 + reg (i).
        const bool strict = diag && (wx == wy);   // need per-element gi<gj
        float sqj[4]; int lj[4];
#pragma unroll
        for (int ni = 0; ni < 4; ni++) {
            int gj = j0 + wx * 64 + ni * 16 + l15;
            sqj[ni] = sq[gj]; lj[ni] = labels[gj];
        }
        float sqi[4][4]; int li[4][4];
#pragma unroll
        for (int mi = 0; mi < 4; mi++)
#pragma unroll
            for (int r = 0; r < 4; r++) {
                int gi = i0 + wy * 64 + mi * 16 + quad * 4 + r;
                sqi[mi][r] = sq[gi]; li[mi][r] = labels[gi];
            }

#pragma unroll
        for (int mi = 0; mi < 4; mi++)
#pragma unroll
            for (int ni = 0; ni < 4; ni++)
#pragma unroll
                for (int r = 0; r < 4; r++) {
                    int ilocal = wy * 64 + mi * 16 + quad * 4 + r;
                    int jlocal = wx * 64 + ni * 16 + l15;
                    bool valid = !strict || (ilocal < jlocal);
                    float d2 = fmaxf(sqi[mi][r] + sqj[ni] - 2.f * acc4[mi][ni][r], 0.f);
                    bool same = (li[mi][r] == lj[ni]);
                    if (valid && same) { pos += d2; cnt += 1.f; }
                    else if (valid && d2 < 4.0f) {   // hinge active iff d < margin (rare)
                        float h = 2.0f - sqrtf(d2);
                        neg += h * h;
                    }
                }
    }

    // block reduction: wave shuffle, LDS across 4 waves, one atomic set/block
#pragma unroll
    for (int off = 32; off > 0; off >>= 1) {
        pos += __shfl_down(pos, off, 64);
        neg += __shfl_down(neg, off, 64);
        cnt += __shfl_down(cnt, off, 64);
    }
    __shared__ float red[3][4];
    if (lane == 0) { red[0][wave] = pos; red[1][wave] = neg; red[2][wave] = cnt; }
    __syncthreads();
    if (tid == 0) {
        atomicAdd(&acc[0], red[0][0] + red[0][1] + red[0][2] + red[0][3]);
        atomicAdd(&acc[1], red[1][0] + red[1][1] + red[1][2] + red[1][3]);
        atomicAdd(&acc[2], red[2][0] + red[2][1] + red[2][2] + red[2][3]);
        __threadfence();                       // adds visible before counter bump
        unsigned prev = atomicAdd((unsigned int*)&acc[3], 1u);
        if (prev == NBLOCKS - 1) {             // last block finalizes
            float P = atomicAdd(&acc[0], 0.f); // atomic reads: device-scope fresh
            float N = atomicAdd(&acc[1], 0.f);
            float C = atomicAdd(&acc[2], 0.f);
            float total = 2.0f * (P + N);      // unordered -> ordered pairs
            out[0] = (C > 0.f) ? total / 67100672.0f : total;  // B*(B-1)
        }
    }
}

extern "C" void kernel_launch(void* const* d_in, const int* in_sizes, int n_in,
                              void* d_out, int out_size, void* d_ws, size_t ws_size,
                              hipStream_t stream) {
    const float* f = (const float*)d_in[0];
    const int* labels = (const int*)d_in[1];
    float* out = (float*)d_out;

    // workspace: bf16 features (2 MB) | sq (32 KB) | acc (4 floats)
    __hip_bfloat16* fb = (__hip_bfloat16*)d_ws;
    float* sq = (float*)((char*)d_ws + (size_t)BN * DD * sizeof(__hip_bfloat16));
    float* acc = sq + BN;

    prep_kernel<<<BN * 64 / 256, 256, 0, stream>>>(f, fb, sq, acc);
    pair_kernel<<<NBLOCKS, 256, 0, stream>>>(fb, labels, sq, acc, out);
}

// Round 4
// 116.070 us; speedup vs baseline: 1.6102x; 1.6102x over previous
//
#include <hip/hip_runtime.h>
#include <hip/hip_bf16.h>

// Contrastive loss, B=8192, D=128, 100 classes, margin=2.
// R4: NO GLOBAL ATOMICS. R1-R3 were serialized on same-address fp32 atomics
// (~15ns each; 6-25k of them predicted 113/133/353us almost exactly).
// Each block stores a (pos,neg) partial to its own slot; tiny reduce kernel sums.
// Gram via bf16 MFMA 16x16x32, fragments loaded directly from L2-resident fb
// (F*F^T: B-fragment of the j-tile loads identically to an A-fragment).
// pos_count>0 always: 8192 rows, 100 classes -> pigeonhole duplicate labels.

#define BN 8192
#define DD 128
#define NTILES 64                              // BN / 128
#define NBLOCKS (NTILES * (NTILES + 1) / 2)    // 2080

typedef __attribute__((ext_vector_type(8))) short bf16x8;   // 8 bf16 = 4 VGPRs
typedef __attribute__((ext_vector_type(4))) float f32x4;

// fp32 -> bf16 (RN); meta[row] = (||row||^2 of rounded values, label as float).
__global__ __launch_bounds__(256) void prep_kernel(const float* __restrict__ f,
        const int* __restrict__ labels, __hip_bfloat16* __restrict__ fb,
        float2* __restrict__ meta) {
    int idx = blockIdx.x * blockDim.x + threadIdx.x;  // BN*64 threads
    int row = idx >> 6, lane = idx & 63;
    float2 v = ((const float2*)(f + (size_t)row * DD))[lane];
    __hip_bfloat162 b2;
    b2.x = __float2bfloat16(v.x);
    b2.y = __float2bfloat16(v.y);
    ((__hip_bfloat162*)(fb + (size_t)row * DD))[lane] = b2;
    float xr = __bfloat162float(b2.x), yr = __bfloat162float(b2.y);
    float s = xr * xr + yr * yr;
#pragma unroll
    for (int off = 32; off > 0; off >>= 1) s += __shfl_down(s, off, 64);
    if (lane == 0) meta[row] = make_float2(s, (float)labels[row]);
}

__global__ __launch_bounds__(256) void pair_kernel(
        const __hip_bfloat16* __restrict__ fb, const float2* __restrict__ meta,
        float2* __restrict__ partial) {
    // triangular decode: block t -> (bx <= by); i-tile = bx, j-tile = by
    const int t = blockIdx.x;
    int by = (int)((sqrtf(8.f * (float)t + 1.f) - 1.f) * 0.5f);
    while ((by + 1) * (by + 2) / 2 <= t) by++;
    while (by * (by + 1) / 2 > t) by--;
    const int bx = t - by * (by + 1) / 2;
    const bool diag = (bx == by);

    const int tid = threadIdx.x;
    const int wave = tid >> 6, lane = tid & 63;
    const int wx = wave & 1, wy = wave >> 1;     // j / i subtile
    const int i0 = bx * 128 + wy * 64;
    const int j0 = by * 128 + wx * 64;
    const int l15 = lane & 15, quad = lane >> 4;

    float pos = 0.f, neg = 0.f;

    // diag blocks: waves with wx<wy cover only gi>gj -> nothing to compute
    if (!(diag && wx < wy)) {
        // epilogue metadata loads issued FIRST so they overlap the MFMA loop
        float2 mj[4];
#pragma unroll
        for (int ni = 0; ni < 4; ni++) mj[ni] = meta[j0 + ni * 16 + l15];
        float2 mi[4][4];
#pragma unroll
        for (int m = 0; m < 4; m++)
#pragma unroll
            for (int r = 0; r < 4; r++) mi[m][r] = meta[i0 + m * 16 + quad * 4 + r];

        f32x4 acc4[4][4];
#pragma unroll
        for (int a = 0; a < 4; a++)
#pragma unroll
            for (int b = 0; b < 4; b++) acc4[a][b] = (f32x4){0.f, 0.f, 0.f, 0.f};

        // K = 128 = 4 k-steps of 32; 16B fragment loads straight from L2.
#pragma unroll
        for (int ks = 0; ks < 4; ks++) {
            const int kofs = ks * 32 + quad * 8;
            bf16x8 af[4], bg[4];
#pragma unroll
            for (int tt = 0; tt < 4; tt++)
                af[tt] = *(const bf16x8*)(fb + (size_t)(i0 + tt * 16 + l15) * DD + kofs);
#pragma unroll
            for (int tt = 0; tt < 4; tt++)
                bg[tt] = *(const bf16x8*)(fb + (size_t)(j0 + tt * 16 + l15) * DD + kofs);
#pragma unroll
            for (int m = 0; m < 4; m++)
#pragma unroll
                for (int n = 0; n < 4; n++)
                    acc4[m][n] = __builtin_amdgcn_mfma_f32_16x16x32_bf16(
                        af[m], bg[n], acc4[m][n], 0, 0, 0);
        }

        // epilogue. C/D: col = lane&15 (j), row = quad*4 + reg (i).
        const bool strict = diag && (wx == wy);  // same 64-subtile: need i<j mask
#pragma unroll
        for (int m = 0; m < 4; m++)
#pragma unroll
            for (int n = 0; n < 4; n++)
#pragma unroll
                for (int r = 0; r < 4; r++) {
                    int il = m * 16 + quad * 4 + r;   // local i within the 64-subtile
                    int jl = n * 16 + l15;            // local j
                    bool valid = !strict || (il < jl);
                    float d2 = fmaxf(mi[m][r].x + mj[n].x - 2.f * acc4[m][n][r], 0.f);
                    if (valid) {
                        if (mi[m][r].y == mj[n].y) pos += d2;
                        else if (d2 < 4.0f) {        // hinge active iff d < margin (rare)
                            float h = 2.0f - sqrtf(d2);
                            neg += h * h;
                        }
                    }
                }
    }

    // block reduction: wave shuffle, LDS across 4 waves, ONE plain store/block
#pragma unroll
    for (int off = 32; off > 0; off >>= 1) {
        pos += __shfl_down(pos, off, 64);
        neg += __shfl_down(neg, off, 64);
    }
    __shared__ float red[2][4];
    if (lane == 0) { red[0][wave] = pos; red[1][wave] = neg; }
    __syncthreads();
    if (tid == 0)
        partial[t] = make_float2(red[0][0] + red[0][1] + red[0][2] + red[0][3],
                                 red[1][0] + red[1][1] + red[1][2] + red[1][3]);
}

__global__ __launch_bounds__(256) void reduce_kernel(
        const float2* __restrict__ partial, float* __restrict__ out) {
    const int tid = threadIdx.x;
    float p = 0.f, n = 0.f;
    for (int i = tid; i < NBLOCKS; i += 256) {
        float2 v = partial[i];
        p += v.x; n += v.y;
    }
#pragma unroll
    for (int off = 32; off > 0; off >>= 1) {
        p += __shfl_down(p, off, 64);
        n += __shfl_down(n, off, 64);
    }
    __shared__ float red[2][4];
    int lane = tid & 63, w = tid >> 6;
    if (lane == 0) { red[0][w] = p; red[1][w] = n; }
    __syncthreads();
    if (tid == 0) {
        float total = 2.0f * (red[0][0] + red[0][1] + red[0][2] + red[0][3] +
                              red[1][0] + red[1][1] + red[1][2] + red[1][3]);
        out[0] = total / 67100672.0f;   // B*(B-1); pos pairs guaranteed (pigeonhole)
    }
}

extern "C" void kernel_launch(void* const* d_in, const int* in_sizes, int n_in,
                              void* d_out, int out_size, void* d_ws, size_t ws_size,
                              hipStream_t stream) {
    const float* f = (const float*)d_in[0];
    const int* labels = (const int*)d_in[1];
    float* out = (float*)d_out;

    // ws: fb 2MB | meta 64KB | partial 16.6KB
    __hip_bfloat16* fb = (__hip_bfloat16*)d_ws;
    float2* meta = (float2*)((char*)d_ws + (size_t)BN * DD * sizeof(__hip_bfloat16));
    float2* partial = meta + BN;

    prep_kernel<<<BN * 64 / 256, 256, 0, stream>>>(f, labels, fb, meta);
    pair_kernel<<<NBLOCKS, 256, 0, stream>>>(fb, meta, partial);
    reduce_kernel<<<1, 256, 0, stream>>>(partial, out);
}

// Round 5
// 89.763 us; speedup vs baseline: 2.0821x; 1.2931x over previous
//
#include <hip/hip_runtime.h>
#include <hip/hip_bf16.h>

// Contrastive loss, B=8192, D=128, 100 classes, margin=2.
// R5: fragment-swizzled feature layout. R4 was latency-bound: each MFMA
// fragment load touched 16 cache lines (16 rows x 256B stride). prep now
// stores features pre-swizzled in MFMA A-fragment order, so every fragment
// load in pair_kernel is ONE contiguous 1KB wave load (16B/lane coalesced).
//   fbp[((p*4 + ks)*64 + lane)*8 + j] = F_bf16[p*16 + (lane&15)][ks*32 + (lane>>4)*8 + j]
// Gram via bf16 MFMA 16x16x32; F*F^T so B-fragments load identically to A.
// No global atomics (R4 lesson: same-address fp32 atomics serialize ~15ns each).
// pos_count>0 always: 8192 rows, 100 classes -> pigeonhole duplicate labels.

#define BN 8192
#define DD 128
#define NTILES 64                              // BN / 128
#define NBLOCKS (NTILES * (NTILES + 1) / 2)    // 2080

typedef __attribute__((ext_vector_type(8))) short bf16x8;   // 8 bf16 = 4 VGPRs
typedef __attribute__((ext_vector_type(4))) float f32x4;

// fp32 -> bf16 (RN), swizzle into fragment order, row norms of rounded values.
// 128 blocks x 256 threads; wave w handles panel p = blk*4 + w (16 rows).
__global__ __launch_bounds__(256) void prep_kernel(const float* __restrict__ f,
        const int* __restrict__ labels, short* __restrict__ fbp,
        float2* __restrict__ meta) {
    const int tid = threadIdx.x;
    const int wave = tid >> 6, lane = tid & 63;
    const int p = blockIdx.x * 4 + wave;
    const int l15 = lane & 15, quad = lane >> 4;
    const int row = p * 16 + l15;

    float s = 0.f;
#pragma unroll
    for (int ks = 0; ks < 4; ks++) {
        const float* src = f + (size_t)row * DD + ks * 32 + quad * 8;
        float4 a = *(const float4*)src;
        float4 b = *(const float4*)(src + 4);
        unsigned short u[8];
        float rv[8] = {a.x, a.y, a.z, a.w, b.x, b.y, b.z, b.w};
#pragma unroll
        for (int j = 0; j < 8; j++) {
            __hip_bfloat16 h = __float2bfloat16(rv[j]);
            u[j] = *(unsigned short*)&h;
            float r = __bfloat162float(h);
            s = fmaf(r, r, s);
        }
        bf16x8 pack;
#pragma unroll
        for (int j = 0; j < 8; j++) pack[j] = (short)u[j];
        *(bf16x8*)(fbp + ((size_t)(p * 4 + ks) * 64 + lane) * 8) = pack;
    }
    // reduce squares across the 4 quads (same l15): xor-shuffle by 16, 32
    s += __shfl_xor(s, 16, 64);
    s += __shfl_xor(s, 32, 64);
    if (quad == 0) meta[row] = make_float2(s, (float)labels[row]);
}

__global__ __launch_bounds__(256) void pair_kernel(
        const short* __restrict__ fbp, const float2* __restrict__ meta,
        float2* __restrict__ partial) {
    // triangular decode: block t -> (bx <= by); i-tile = bx, j-tile = by
    const int t = blockIdx.x;
    int by = (int)((sqrtf(8.f * (float)t + 1.f) - 1.f) * 0.5f);
    while ((by + 1) * (by + 2) / 2 <= t) by++;
    while (by * (by + 1) / 2 > t) by--;
    const int bx = t - by * (by + 1) / 2;
    const bool diag = (bx == by);

    const int tid = threadIdx.x;
    const int wave = tid >> 6, lane = tid & 63;
    const int wx = wave & 1, wy = wave >> 1;     // j / i subtile
    const int i0 = bx * 128 + wy * 64;
    const int j0 = by * 128 + wx * 64;
    const int ip = i0 >> 4, jp = j0 >> 4;        // panel indices
    const int l15 = lane & 15, quad = lane >> 4;

    float pos = 0.f, neg = 0.f;

    // diag blocks: waves with wx<wy cover only gi>gj -> nothing to compute
    if (!(diag && wx < wy)) {
        // epilogue metadata loads issued FIRST so they overlap the MFMA loop
        float2 mj[4];
#pragma unroll
        for (int ni = 0; ni < 4; ni++) mj[ni] = meta[j0 + ni * 16 + l15];
        float2 mi[4][4];
#pragma unroll
        for (int m = 0; m < 4; m++)
#pragma unroll
            for (int r = 0; r < 4; r++) mi[m][r] = meta[i0 + m * 16 + quad * 4 + r];

        f32x4 acc4[4][4];
#pragma unroll
        for (int a = 0; a < 4; a++)
#pragma unroll
            for (int b = 0; b < 4; b++) acc4[a][b] = (f32x4){0.f, 0.f, 0.f, 0.f};

        // K = 128 = 4 k-steps of 32; each fragment = ONE contiguous 1KB wave load
#pragma unroll
        for (int ks = 0; ks < 4; ks++) {
            bf16x8 af[4], bg[4];
#pragma unroll
            for (int tt = 0; tt < 4; tt++)
                af[tt] = *(const bf16x8*)(fbp +
                    ((size_t)((ip + tt) * 4 + ks) * 64 + lane) * 8);
#pragma unroll
            for (int tt = 0; tt < 4; tt++)
                bg[tt] = *(const bf16x8*)(fbp +
                    ((size_t)((jp + tt) * 4 + ks) * 64 + lane) * 8);
#pragma unroll
            for (int m = 0; m < 4; m++)
#pragma unroll
                for (int n = 0; n < 4; n++)
                    acc4[m][n] = __builtin_amdgcn_mfma_f32_16x16x32_bf16(
                        af[m], bg[n], acc4[m][n], 0, 0, 0);
        }

        // epilogue. C/D: col = lane&15 (j), row = quad*4 + reg (i).
        const bool strict = diag && (wx == wy);  // same 64-subtile: need i<j mask
#pragma unroll
        for (int m = 0; m < 4; m++)
#pragma unroll
            for (int n = 0; n < 4; n++)
#pragma unroll
                for (int r = 0; r < 4; r++) {
                    int il = m * 16 + quad * 4 + r;   // local i within 64-subtile
                    int jl = n * 16 + l15;            // local j
                    bool valid = !strict || (il < jl);
                    float d2 = fmaxf(mi[m][r].x + mj[n].x - 2.f * acc4[m][n][r], 0.f);
                    if (valid) {
                        if (mi[m][r].y == mj[n].y) pos += d2;
                        else if (d2 < 4.0f) {        // hinge active iff d < margin
                            float h = 2.0f - sqrtf(d2);
                            neg += h * h;
                        }
                    }
                }
    }

    // block reduction: wave shuffle, LDS across 4 waves, ONE plain store/block
#pragma unroll
    for (int off = 32; off > 0; off >>= 1) {
        pos += __shfl_down(pos, off, 64);
        neg += __shfl_down(neg, off, 64);
    }
    __shared__ float red[2][4];
    if (lane == 0) { red[0][wave] = pos; red[1][wave] = neg; }
    __syncthreads();
    if (tid == 0)
        partial[t] = make_float2(red[0][0] + red[0][1] + red[0][2] + red[0][3],
                                 red[1][0] + red[1][1] + red[1][2] + red[1][3]);
}

__global__ __launch_bounds__(256) void reduce_kernel(
        const float2* __restrict__ partial, float* __restrict__ out) {
    const int tid = threadIdx.x;
    float p = 0.f, n = 0.f;
    for (int i = tid; i < NBLOCKS; i += 256) {
        float2 v = partial[i];
        p += v.x; n += v.y;
    }
#pragma unroll
    for (int off = 32; off > 0; off >>= 1) {
        p += __shfl_down(p, off, 64);
        n += __shfl_down(n, off, 64);
    }
    __shared__ float red[2][4];
    int lane = tid & 63, w = tid >> 6;
    if (lane == 0) { red[0][w] = p; red[1][w] = n; }
    __syncthreads();
    if (tid == 0) {
        float total = 2.0f * (red[0][0] + red[0][1] + red[0][2] + red[0][3] +
                              red[1][0] + red[1][1] + red[1][2] + red[1][3]);
        out[0] = total / 67100672.0f;   // B*(B-1); pos pairs guaranteed (pigeonhole)
    }
}

extern "C" void kernel_launch(void* const* d_in, const int* in_sizes, int n_in,
                              void* d_out, int out_size, void* d_ws, size_t ws_size,
                              hipStream_t stream) {
    const float* f = (const float*)d_in[0];
    const int* labels = (const int*)d_in[1];
    float* out = (float*)d_out;

    // ws: fbp 2MB | meta 64KB | partial 16.6KB
    short* fbp = (short*)d_ws;
    float2* meta = (float2*)((char*)d_ws + (size_t)BN * DD * sizeof(short));
    float2* partial = meta + BN;

    prep_kernel<<<BN / 64, 256, 0, stream>>>(f, labels, fbp, meta);
    pair_kernel<<<NBLOCKS, 256, 0, stream>>>(fbp, meta, partial);
    reduce_kernel<<<1, 256, 0, stream>>>(partial, out);
}

// Round 6
// 88.190 us; speedup vs baseline: 2.1192x; 1.0178x over previous
//
#include <hip/hip_runtime.h>
#include <hip/hip_bf16.h>

// Contrastive loss, B=8192, D=128, 100 classes, margin=2.
// R6: (a) pair_kernel gets a 2-deep register double-buffer on the MFMA
// fragments -- 16 fragment loads in flight before the first MFMA batch, next
// k-step's loads issue while current MFMAs run (R5 held one frag set at
// VGPR=88 and ate a full vmcnt(0) L2-latency stall per k-step).
// (b) prep_kernel back to full parallelism: 512 blocks, coalesced 8KB/block
// global reads, LDS transpose (272B row stride: 16B-aligned, even bank
// spread), coalesced 1KB/wave fragment-order writes. Layout unchanged:
//   fbp[((p*4+ks)*64+lane)*8+j] = F_bf16[p*16+(lane&15)][ks*32+(lane>>4)*8+j]
// Known harness floor: ~45us/iter (d_ws 268MB 0xAA poison fill ~41us + restore).
// No global atomics (R4: same-address fp32 atomics serialize ~15ns each).
// pos_count>0 always: 8192 rows, 100 classes -> pigeonhole duplicate labels.

#define BN 8192
#define DD 128
#define NTILES 64                              // BN / 128
#define NBLOCKS (NTILES * (NTILES + 1) / 2)    // 2080
#define LS 136                                 // prep LDS row stride (shorts)

typedef __attribute__((ext_vector_type(8))) short bf16x8;   // 8 bf16 = 4 VGPRs
typedef __attribute__((ext_vector_type(4))) float f32x4;

// One block per 16-row panel. Coalesced read -> bf16 -> LDS transpose ->
// coalesced fragment-order write. Also emits (norm^2, label) meta.
__global__ __launch_bounds__(256) void prep_kernel(const float* __restrict__ f,
        const int* __restrict__ labels, short* __restrict__ fbp,
        float2* __restrict__ meta) {
    const int tid = threadIdx.x;
    const int p = blockIdx.x;                  // panel index (16 rows)
    __shared__ unsigned short ls[16][LS];

    const int r = tid >> 4;                    // row in panel (16 threads/row)
    const int c = (tid & 15) * 8;              // col of this thread's 8 floats
    const float* src = f + ((size_t)p * 16 + r) * DD + c;
    float4 a = *(const float4*)src;
    float4 b = *(const float4*)(src + 4);
    float rv[8] = {a.x, a.y, a.z, a.w, b.x, b.y, b.z, b.w};
    float s = 0.f;
#pragma unroll
    for (int j = 0; j < 8; j++) {
        __hip_bfloat16 h = __float2bfloat16(rv[j]);
        ls[r][c + j] = *(unsigned short*)&h;
        float rr = __bfloat162float(h);
        s = fmaf(rr, rr, s);
    }
    // row norm: reduce across the 16 consecutive lanes of this row
#pragma unroll
    for (int off = 8; off > 0; off >>= 1) s += __shfl_down(s, off, 16);
    if ((tid & 15) == 0) meta[p * 16 + r] = make_float2(s, (float)labels[p * 16 + r]);
    __syncthreads();

    // wave w = k-step ks; 16B/lane LDS read, 1KB contiguous global write
    const int w = tid >> 6, lane = tid & 63;
    const int l15 = lane & 15, quad = lane >> 4;
    bf16x8 pack = *(const bf16x8*)&ls[l15][w * 32 + quad * 8];
    *(bf16x8*)(fbp + ((size_t)(p * 4 + w) * 64 + lane) * 8) = pack;
}

__global__ __launch_bounds__(256) void pair_kernel(
        const short* __restrict__ fbp, const float2* __restrict__ meta,
        float2* __restrict__ partial) {
    // triangular decode: block t -> (bx <= by); i-tile = bx, j-tile = by
    const int t = blockIdx.x;
    int by = (int)((sqrtf(8.f * (float)t + 1.f) - 1.f) * 0.5f);
    while ((by + 1) * (by + 2) / 2 <= t) by++;
    while (by * (by + 1) / 2 > t) by--;
    const int bx = t - by * (by + 1) / 2;
    const bool diag = (bx == by);

    const int tid = threadIdx.x;
    const int wave = tid >> 6, lane = tid & 63;
    const int wx = wave & 1, wy = wave >> 1;     // j / i subtile
    const int i0 = bx * 128 + wy * 64;
    const int j0 = by * 128 + wx * 64;
    const int ip = i0 >> 4, jp = j0 >> 4;        // panel indices
    const int l15 = lane & 15, quad = lane >> 4;

    float pos = 0.f, neg = 0.f;

    if (!(diag && wx < wy)) {    // diag blocks: wx<wy waves cover only gi>gj
        // epilogue metadata loads first: long latency tolerated
        float2 mj[4];
#pragma unroll
        for (int ni = 0; ni < 4; ni++) mj[ni] = meta[j0 + ni * 16 + l15];
        float2 mi[4][4];
#pragma unroll
        for (int m = 0; m < 4; m++)
#pragma unroll
            for (int r = 0; r < 4; r++) mi[m][r] = meta[i0 + m * 16 + quad * 4 + r];

        f32x4 acc4[4][4];
#pragma unroll
        for (int a = 0; a < 4; a++)
#pragma unroll
            for (int b = 0; b < 4; b++) acc4[a][b] = (f32x4){0.f, 0.f, 0.f, 0.f};

        // fragment loads: one contiguous 1KB wave load each
        auto loadf = [&](int ks, bf16x8* af, bf16x8* bg) {
#pragma unroll
            for (int tt = 0; tt < 4; tt++)
                af[tt] = *(const bf16x8*)(fbp +
                    ((size_t)((ip + tt) * 4 + ks) * 64 + lane) * 8);
#pragma unroll
            for (int tt = 0; tt < 4; tt++)
                bg[tt] = *(const bf16x8*)(fbp +
                    ((size_t)((jp + tt) * 4 + ks) * 64 + lane) * 8);
        };
        auto mfma16 = [&](bf16x8* af, bf16x8* bg) {
#pragma unroll
            for (int m = 0; m < 4; m++)
#pragma unroll
                for (int n = 0; n < 4; n++)
                    acc4[m][n] = __builtin_amdgcn_mfma_f32_16x16x32_bf16(
                        af[m], bg[n], acc4[m][n], 0, 0, 0);
        };

        // 2-deep software pipeline over the 4 k-steps (K=128)
        bf16x8 a0[4], b0[4], a1[4], b1[4];
        loadf(0, a0, b0);
        loadf(1, a1, b1);
        mfma16(a0, b0);
        loadf(2, a0, b0);
        mfma16(a1, b1);
        loadf(3, a1, b1);
        mfma16(a0, b0);
        mfma16(a1, b1);

        // epilogue. C/D: col = lane&15 (j), row = quad*4 + reg (i).
        const bool strict = diag && (wx == wy);  // same 64-subtile: need i<j
#pragma unroll
        for (int m = 0; m < 4; m++)
#pragma unroll
            for (int n = 0; n < 4; n++)
#pragma unroll
                for (int r = 0; r < 4; r++) {
                    int il = m * 16 + quad * 4 + r;
                    int jl = n * 16 + l15;
                    bool valid = !strict || (il < jl);
                    float d2 = fmaxf(mi[m][r].x + mj[n].x - 2.f * acc4[m][n][r], 0.f);
                    if (valid) {
                        if (mi[m][r].y == mj[n].y) pos += d2;
                        else if (d2 < 4.0f) {        // hinge active iff d < margin
                            float h = 2.0f - sqrtf(d2);
                            neg += h * h;
                        }
                    }
                }
    }

    // block reduction: wave shuffle, LDS across 4 waves, ONE plain store/block
#pragma unroll
    for (int off = 32; off > 0; off >>= 1) {
        pos += __shfl_down(pos, off, 64);
        neg += __shfl_down(neg, off, 64);
    }
    __shared__ float red[2][4];
    if (lane == 0) { red[0][wave] = pos; red[1][wave] = neg; }
    __syncthreads();
    if (tid == 0)
        partial[t] = make_float2(red[0][0] + red[0][1] + red[0][2] + red[0][3],
                                 red[1][0] + red[1][1] + red[1][2] + red[1][3]);
}

__global__ __launch_bounds__(256) void reduce_kernel(
        const float2* __restrict__ partial, float* __restrict__ out) {
    const int tid = threadIdx.x;
    float p = 0.f, n = 0.f;
    for (int i = tid; i < NBLOCKS; i += 256) {
        float2 v = partial[i];
        p += v.x; n += v.y;
    }
#pragma unroll
    for (int off = 32; off > 0; off >>= 1) {
        p += __shfl_down(p, off, 64);
        n += __shfl_down(n, off, 64);
    }
    __shared__ float red[2][4];
    int lane = tid & 63, w = tid >> 6;
    if (lane == 0) { red[0][w] = p; red[1][w] = n; }
    __syncthreads();
    if (tid == 0) {
        float total = 2.0f * (red[0][0] + red[0][1] + red[0][2] + red[0][3] +
                              red[1][0] + red[1][1] + red[1][2] + red[1][3]);
        out[0] = total / 67100672.0f;   // B*(B-1); pos pairs guaranteed (pigeonhole)
    }
}

extern "C" void kernel_launch(void* const* d_in, const int* in_sizes, int n_in,
                              void* d_out, int out_size, void* d_ws, size_t ws_size,
                              hipStream_t stream) {
    const float* f = (const float*)d_in[0];
    const int* labels = (const int*)d_in[1];
    float* out = (float*)d_out;

    // ws: fbp 2MB | meta 64KB | partial 16.6KB
    short* fbp = (short*)d_ws;
    float2* meta = (float2*)((char*)d_ws + (size_t)BN * DD * sizeof(short));
    float2* partial = meta + BN;

    prep_kernel<<<BN / 16, 256, 0, stream>>>(f, labels, fbp, meta);
    pair_kernel<<<NBLOCKS, 256, 0, stream>>>(fbp, meta, partial);
    reduce_kernel<<<1, 256, 0, stream>>>(partial, out);
}